// Round 6
// baseline (347.476 us; speedup 1.0000x reference)
//
#include <hip/hip_runtime.h>
#include <hip/hip_bf16.h>
#include <math.h>

#define HEADS  8
#define TT     32
#define DMODEL 512
#define HWSZ   1024
#define TSTRIDE (HWSZ*DMODEL)

#define NQKV (3*DMODEL*DMODEL)   // 786432
#define NOUT (DMODEL*DMODEL)     // 262144
#define NTAB 512

typedef __attribute__((ext_vector_type(8)))  short bf16x8;
typedef __attribute__((ext_vector_type(16))) float f32x16;
typedef __attribute__((ext_vector_type(4)))  short s16x4;

__device__ __forceinline__ unsigned short f2bf(float f) {   // RNE f32->bf16
    unsigned int u = __builtin_bit_cast(unsigned int, f);
    u += 0x7FFFu + ((u >> 16) & 1u);
    return (unsigned short)(u >> 16);
}

__device__ __forceinline__ f32x16 fz16() {
    f32x16 v = {0.f,0.f,0.f,0.f,0.f,0.f,0.f,0.f,0.f,0.f,0.f,0.f,0.f,0.f,0.f,0.f};
    return v;
}

// ---------------- prep: weights -> bf16 MFMA32 B-fragment order + rope tables --
// B-frag layout (32x32x16): lane l holds B[k = ks*16 + (l>>5)*8 + i][n = ct*32 + (l&31)]
// 1KB block per (ct, ks): element ((ct*32 + ks)*64 + lane)*8 + i
__global__ __launch_bounds__(256)
void taa_prep(const float* __restrict__ wqkv, const float* __restrict__ wout,
              unsigned short* __restrict__ ws) {
    long i = (long)blockIdx.x * 256 + threadIdx.x;
    unsigned short* wqf = ws;
    unsigned short* wof = ws + NQKV;
    float* cs = (float*)(wof + NOUT);
    float* sn = cs + NTAB;
    if (i < NQKV) {
        int i8 = (int)(i & 7), lane = (int)((i >> 3) & 63), blk = (int)(i >> 9);
        int ks = blk & 31, ct = blk >> 5;          // ct < 48
        int n = ct * 32 + (lane & 31);
        int k = ks * 16 + (lane >> 5) * 8 + i8;
        wqf[i] = f2bf(wqkv[(long)k * 1536 + n]);
    } else if (i < NQKV + NOUT) {
        long j = i - NQKV;
        int i8 = (int)(j & 7), lane = (int)((j >> 3) & 63), blk = (int)(j >> 9);
        int ks = blk & 31, ct = blk >> 5;          // ct < 16
        int n = ct * 32 + (lane & 31);
        int k = ks * 16 + (lane >> 5) * 8 + i8;
        wof[j] = f2bf(wout[(long)k * 512 + n]);
    } else if (i < NQKV + NOUT + NTAB) {
        int j = (int)(i - NQKV - NOUT);
        int t = j >> 4, f = j & 15;
        float inv = powf(10000.f, -(float)(2 * f) / 32.f);
        float sv, cv;
        sincosf((float)t * inv, &sv, &cv);
        cs[j] = cv; sn[j] = sv;
    }
}

// ---------------- LDS layout (bytes) ------------------------------------------
// X  [2g][32][512]bf16 swizzled rows (1024B stride)           65536
// Q  [2g][2h][32][64]bf16 128B stride, RS swizzle             16384
// K  same                                                     16384
// V^T[2g][2h][64][32]bf16 64B stride, VS swizzle              16384
// PV [2g][32][128]bf16 256B stride, PS swizzle                16384
#define X_OFF  0
#define Q_OFF  65536
#define K_OFF  81920
#define V_OFF  98304
#define PV_OFF 114688
#define CS_OFF 131072
#define SN_OFF 133120
#define LDS_SZ 135168

#define XS(g,r,cB) (X_OFF + ((g)<<15) + ((r)<<10) + ((cB) ^ (((r)&7)<<4)))
#define RS(base,r,cB) ((base) + ((r)<<7) + ((cB) ^ (((r)&7)<<4)))
#define VS(base,d,cB) ((base) + ((d)<<6) + ((cB) ^ (((d)&7)<<3)))
#define PS(g,r,cB) (PV_OFF + ((g)<<13) + ((r)<<8) + ((cB) ^ (((r)&7)<<4)))

#define MFMA32(a, b, c) __builtin_amdgcn_mfma_f32_32x32x16_bf16((a), (b), (c), 0, 0, 0)

__global__ __launch_bounds__(512, 2)
void taa_main(const float* __restrict__ x,
              const unsigned short* __restrict__ ws,
              const float* __restrict__ b_out,
              float* __restrict__ out) {
    extern __shared__ __align__(16) unsigned char smem[];

    const unsigned short* wqf = ws;
    const unsigned short* wof = ws + NQKV;
    const float* cs_gl = (const float*)(wof + NOUT);
    const float* sn_gl = cs_gl + NTAB;

    const int tid  = threadIdx.x;
    const int lane = tid & 63;
    const int wv   = tid >> 6;                 // wave 0..7
    const int hf   = lane >> 5;                // half-wave 0/1
    const int tq   = lane & 31;

    const int n0 = blockIdx.x * 2;
    const long long base0 = ((long long)(n0 >> 10) * (TT * HWSZ) + (n0 & 1023)) * DMODEL;
    const int n1 = n0 + 1;
    const long long base1 = ((long long)(n1 >> 10) * (TT * HWSZ) + (n1 & 1023)) * DMODEL;

    float* cs_l = (float*)(smem + CS_OFF);
    float* sn_l = (float*)(smem + SN_OFF);
    for (int i = tid; i < NTAB; i += 512) { cs_l[i] = cs_gl[i]; sn_l[i] = sn_gl[i]; }

    // ---- stage x (both groups): fp32 global -> bf16 swizzled LDS ----
    for (int idx = tid; idx < 4096; idx += 512) {
        int g  = idx >> 11;
        int r  = (idx >> 6) & 31;
        int c8 = idx & 63;
        long long bg = g ? base1 : base0;
        const float4* src = (const float4*)(x + bg + (long long)r * TSTRIDE + c8 * 8);
        float4 f0 = src[0], f1 = src[1];
        s16x4 lo, hi;
        lo[0] = (short)f2bf(f0.x); lo[1] = (short)f2bf(f0.y);
        lo[2] = (short)f2bf(f0.z); lo[3] = (short)f2bf(f0.w);
        hi[0] = (short)f2bf(f1.x); hi[1] = (short)f2bf(f1.y);
        hi[2] = (short)f2bf(f1.z); hi[3] = (short)f2bf(f1.w);
        int a = XS(g, r, c8 * 16);
        *(s16x4*)(smem + a)     = lo;
        *(s16x4*)(smem + a + 8) = hi;
    }

    f32x16 oac[2][2];                          // [col-tile jj][group]
    oac[0][0] = fz16(); oac[0][1] = fz16();
    oac[1][0] = fz16(); oac[1][1] = fz16();

    __syncthreads();

    // wave's fixed role: group g, head-in-pair hh, d-half dh
    const int g  = wv >> 2;
    const int hh = (wv >> 1) & 1;
    const int dh = wv & 1;

    for (int it = 0; it < 4; ++it) {
        const int hd = it * 2 + hh;            // global head

        // ===== qkv: one A-stream feeds 3 MFMA chains (q,k,v) per K-step =======
        const unsigned short* pq = wqf + ((long)((      hd * 2 + dh) * 32)) * 512 + lane * 8;
        const unsigned short* pk = wqf + ((long)((16 + hd * 2 + dh) * 32)) * 512 + lane * 8;
        const unsigned short* pv = wqf + ((long)((32 + hd * 2 + dh) * 32)) * 512 + lane * 8;
        f32x16 aq = fz16(), ak = fz16(), av = fz16();
        #pragma unroll 4
        for (int ks = 0; ks < 32; ++ks) {
            bf16x8 a   = *(const bf16x8*)(smem + XS(g, tq, ks * 32 + hf * 16));
            bf16x8 wq_ = *(const bf16x8*)(pq + (long)ks * 512);
            bf16x8 wk_ = *(const bf16x8*)(pk + (long)ks * 512);
            bf16x8 wv_ = *(const bf16x8*)(pv + (long)ks * 512);
            aq = MFMA32(a, wq_, aq);
            ak = MFMA32(a, wk_, ak);
            av = MFMA32(a, wv_, av);
        }
        // epilogue: q,k (RoPE on d-half 0), v -> V^T
        {
            int qb = Q_OFF + (g * 2 + hh) * 4096;
            int kb = K_OFF + (g * 2 + hh) * 4096;
            if (dh == 0) {                     // dims 0..31: all rotary
                #pragma unroll
                for (int r = 0; r < 16; ++r) {
                    int t = (r & 3) + 8 * (r >> 2) + 4 * hf;
                    float cv = cs_l[t * 16 + (tq >> 1)];
                    float sv = sn_l[t * 16 + (tq >> 1)];
                    float vq = aq[r], pq2 = __shfl_xor(vq, 1, 64);
                    float rq = (tq & 1) ? (vq * cv + pq2 * sv) : (vq * cv - pq2 * sv);
                    *(unsigned short*)(smem + RS(qb, t, tq * 2)) = f2bf(rq);
                    float vk = ak[r], pk2 = __shfl_xor(vk, 1, 64);
                    float rk = (tq & 1) ? (vk * cv + pk2 * sv) : (vk * cv - pk2 * sv);
                    *(unsigned short*)(smem + RS(kb, t, tq * 2)) = f2bf(rk);
                }
            } else {                           // dims 32..63: pass-through
                #pragma unroll
                for (int r = 0; r < 16; ++r) {
                    int t = (r & 3) + 8 * (r >> 2) + 4 * hf;
                    *(unsigned short*)(smem + RS(qb, t, 64 + tq * 2)) = f2bf(aq[r]);
                    *(unsigned short*)(smem + RS(kb, t, 64 + tq * 2)) = f2bf(ak[r]);
                }
            }
            int vb = V_OFF + (g * 2 + hh) * 4096;
            int d  = dh * 32 + tq;
            #pragma unroll
            for (int c = 0; c < 4; ++c) {      // regs c*4..c*4+3 = t (c*8+4hf)..+3
                s16x4 pkk;
                pkk[0] = (short)f2bf(av[c * 4 + 0]);
                pkk[1] = (short)f2bf(av[c * 4 + 1]);
                pkk[2] = (short)f2bf(av[c * 4 + 2]);
                pkk[3] = (short)f2bf(av[c * 4 + 3]);
                *(s16x4*)(smem + VS(vb, d, c * 16 + hf * 8)) = pkk;
            }
        }
        __syncthreads();

        // ===== attention (register-only, wave = its own (g,hh,dh)) ============
        {
            int qr = Q_OFF + (g * 2 + hh) * 4096;
            int kr = K_OFF + (g * 2 + hh) * 4096;
            int vr = V_OFF + (g * 2 + hh) * 4096;
            f32x16 sc = fz16();
            #pragma unroll
            for (int j = 0; j < 4; ++j) {
                bf16x8 aK = *(const bf16x8*)(smem + RS(kr, tq, j * 32 + hf * 16));
                bf16x8 bQ = *(const bf16x8*)(smem + RS(qr, tq, j * 32 + hf * 16));
                sc = MFMA32(aK, bQ, sc);
            }
            float pe[16];
            float mx = -1e30f;
            #pragma unroll
            for (int r = 0; r < 16; ++r) {
                int tk = (r & 3) + 8 * (r >> 2) + 4 * hf;
                float v = (tk <= tq) ? sc[r] * 0.125f : -1e30f;
                pe[r] = v;
                mx = fmaxf(mx, v);
            }
            mx = fmaxf(mx, __shfl_xor(mx, 32, 64));
            float sum = 0.f;
            #pragma unroll
            for (int r = 0; r < 16; ++r) {
                float e = __expf(pe[r] - mx);
                pe[r] = e;
                sum += e;
            }
            sum += __shfl_xor(sum, 32, 64);
            float inv = 1.f / sum;
            bf16x8 pa0, pa1;
            #pragma unroll
            for (int i2 = 0; i2 < 8; ++i2) {
                pa0[i2] = (short)f2bf(pe[i2] * inv);
                pa1[i2] = (short)f2bf(pe[8 + i2] * inv);
            }
            int d = dh * 32 + tq;
            f32x16 o = fz16();
            {
                s16x4 lo = *(const s16x4*)(smem + VS(vr, d, 8 * hf));
                s16x4 hi = *(const s16x4*)(smem + VS(vr, d, 16 + 8 * hf));
                bf16x8 bv;
                bv[0] = lo[0]; bv[1] = lo[1]; bv[2] = lo[2]; bv[3] = lo[3];
                bv[4] = hi[0]; bv[5] = hi[1]; bv[6] = hi[2]; bv[7] = hi[3];
                o = MFMA32(pa0, bv, o);
            }
            {
                s16x4 lo = *(const s16x4*)(smem + VS(vr, d, 32 + 8 * hf));
                s16x4 hi = *(const s16x4*)(smem + VS(vr, d, 48 + 8 * hf));
                bf16x8 bv;
                bv[0] = lo[0]; bv[1] = lo[1]; bv[2] = lo[2]; bv[3] = lo[3];
                bv[4] = hi[0]; bv[5] = hi[1]; bv[6] = hi[2]; bv[7] = hi[3];
                o = MFMA32(pa1, bv, o);
            }
            #pragma unroll
            for (int r = 0; r < 16; ++r) {
                int t = (r & 3) + 8 * (r >> 2) + 4 * hf;
                *(unsigned short*)(smem + PS(g, t, (hh * 64 + d) * 2)) = f2bf(o[r]);
            }
        }
        __syncthreads();

        // ===== out-projection: wave = 2 col-tiles x both groups ===============
        {
            #pragma unroll
            for (int ksl = 0; ksl < 8; ++ksl) {
                int ksg = it * 8 + ksl;        // K range = this head pair
                bf16x8 a0 = *(const bf16x8*)(smem + PS(0, tq, ksl * 32 + hf * 16));
                bf16x8 a1 = *(const bf16x8*)(smem + PS(1, tq, ksl * 32 + hf * 16));
                bf16x8 b0 = *(const bf16x8*)(wof + ((long)(wv * 32 + ksg)) * 512 + lane * 8);
                bf16x8 b1 = *(const bf16x8*)(wof + ((long)((wv + 8) * 32 + ksg)) * 512 + lane * 8);
                oac[0][0] = MFMA32(a0, b0, oac[0][0]);
                oac[0][1] = MFMA32(a1, b0, oac[0][1]);
                oac[1][0] = MFMA32(a0, b1, oac[1][0]);
                oac[1][1] = MFMA32(a1, b1, oac[1][1]);
            }
        }
        // no barrier needed: next-iter qkv writes Q/K/V (readers done at attn
        // barrier); next-iter attn writes PV only after next qkv barrier.
    }

    // ===== write out (+bias) =====
    #pragma unroll
    for (int jj = 0; jj < 2; ++jj) {
        int coln = (wv + 8 * jj) * 32 + tq;
        float bias = b_out[coln];
        #pragma unroll
        for (int gg = 0; gg < 2; ++gg) {
            long long bg = gg ? base1 : base0;
            #pragma unroll
            for (int r = 0; r < 16; ++r) {
                int t = (r & 3) + 8 * (r >> 2) + 4 * hf;
                out[bg + (long long)t * TSTRIDE + coln] = oac[jj][gg][r] + bias;
            }
        }
    }
}

extern "C" void kernel_launch(void* const* d_in, const int* in_sizes, int n_in,
                              void* d_out, int out_size, void* d_ws, size_t ws_size,
                              hipStream_t stream) {
    const float* x     = (const float*)d_in[0];
    const float* w_qkv = (const float*)d_in[1];
    const float* w_out = (const float*)d_in[2];
    const float* b_out = (const float*)d_in[3];
    float* out = (float*)d_out;
    (void)in_sizes; (void)n_in; (void)out_size; (void)ws_size;

    unsigned short* ws = (unsigned short*)d_ws;   // ~2.1 MB

    taa_prep<<<dim3(4098), dim3(256), 0, stream>>>(w_qkv, w_out, ws);
    taa_main<<<dim3(1024), dim3(512), LDS_SZ, stream>>>(x, ws, b_out, out);
}